// Round 8
// baseline (7355.309 us; speedup 1.0000x reference)
//
#include <hip/hip_runtime.h>
#include <hip/hip_fp16.h>

// Problem constants (from reference)
#define EDIM 256
#define SLEN 64
#define TLEN 512
#define NT 1024
#define NWAVES 16

// ---- fp16 pair helpers (phase-C signal copy only) ----
__device__ __forceinline__ float2 h2f2(unsigned int u) {
    __half2 h = *reinterpret_cast<__half2*>(&u);
    return __half22float2(h);
}
__device__ __forceinline__ unsigned int pack2h(float a, float b) {
    __half ha = __float2half_rn(a), hb = __float2half_rn(b);
    unsigned short ua = *reinterpret_cast<unsigned short*>(&ha);
    unsigned short ub = *reinterpret_cast<unsigned short*>(&hb);
    return (unsigned int)ua | ((unsigned int)ub << 16);
}

// ---- wave/block reductions (softmax + LN only) ----
__device__ __forceinline__ float wred_sum(float v) {
#pragma unroll
    for (int m = 32; m > 0; m >>= 1) v += __shfl_xor(v, m, 64);
    return v;
}
__device__ __forceinline__ float wred_max(float v) {
#pragma unroll
    for (int m = 32; m > 0; m >>= 1) v = fmaxf(v, __shfl_xor(v, m, 64));
    return v;
}
__device__ __forceinline__ float block_sum(float v, float* scr, int tid) {
    v = wred_sum(v);
    if ((tid & 63) == 0) scr[tid >> 6] = v;
    __syncthreads();
    if (tid == 0) {
        float s = scr[0];
#pragma unroll
        for (int i = 1; i < NWAVES; ++i) s += scr[i];
        scr[0] = s;
    }
    __syncthreads();
    float r = scr[0];
    __syncthreads();
    return r;
}
__device__ __forceinline__ float block_max(float v, float* scr, int tid) {
    v = wred_max(v);
    if ((tid & 63) == 0) scr[tid >> 6] = v;
    __syncthreads();
    if (tid == 0) {
        float s = scr[0];
#pragma unroll
        for (int i = 1; i < NWAVES; ++i) s = fmaxf(s, scr[i]);
        scr[0] = s;
    }
    __syncthreads();
    float r = scr[0];
    __syncthreads();
    return r;
}

// ---- pre-pass 1: batched fp32 transpose  out[z][c][r] = in[z][r][c] ----
__global__ __launch_bounds__(256) void transpose_b_kernel(
    const float* __restrict__ in, float* __restrict__ out, int R, int C)
{
    __shared__ float tile[64][65];
    const float* inb = in + (size_t)blockIdx.z * R * C;
    float* outb = out + (size_t)blockIdx.z * R * C;
    const int r0 = blockIdx.y * 64;
    const int c0 = blockIdx.x * 64;
#pragma unroll
    for (int i = threadIdx.x; i < 64 * 64; i += 256) {
        int r = i >> 6, c = i & 63;
        tile[r][c] = inb[(size_t)(r0 + r) * C + (c0 + c)];
    }
    __syncthreads();
#pragma unroll
    for (int i = threadIdx.x; i < 64 * 64; i += 256) {
        int c = i >> 6, r = i & 63;
        outb[(size_t)(c0 + c) * R + (r0 + r)] = tile[r][c];
    }
}

// ---- pre-pass 2: pack fp16 pairs along t of signal ----
// in: [B][T][E] fp32 -> out: [B][T/2][E] uint, out[tt][e] = pack(in[2tt][e], in[2tt+1][e])
__global__ __launch_bounds__(256) void pack_rows_h_kernel(
    const float* __restrict__ in, unsigned int* __restrict__ out)
{
    size_t id = (size_t)blockIdx.x * 256 + threadIdx.x;  // B*(T/2)*E total
    int e   = (int)(id & (EDIM - 1));
    size_t zt = id >> 8;
    int tt  = (int)(zt & (TLEN / 2 - 1));
    int z   = (int)(zt >> 8);
    const float* p = in + ((size_t)z * TLEN + 2 * tt) * EDIM + e;
    out[id] = pack2h(p[0], p[EDIM]);
}

__global__ __launch_bounds__(NT) void gru_decoder_kernel(
    const float* __restrict__ sigT,         // [B,E,T] fp32  (phase B, score path: fp32)
    const unsigned int* __restrict__ sigC2, // [B,T/2,E] fp16x2 (phase C)
    const float* __restrict__ bases,        // [B,S,E]
    const int* __restrict__ mask,           // [B,T] int32 (nonzero = masked)
    const float* __restrict__ WwT,          // [E,E] fp32 (WwT[k][j] = Ww[j][k])
    const float* __restrict__ Wb,           // [E]
    const float* __restrict__ lng,          // [2E]
    const float* __restrict__ lnb,          // [2E]
    const float* __restrict__ wihT,         // [2E,3E] fp32
    const float* __restrict__ bih,          // [3E]
    const float* __restrict__ whhT,         // [E,3E] fp32
    const float* __restrict__ bhh,          // [3E]
    const float* __restrict__ hinit,        // [E]
    float* __restrict__ out)                // [B,S,E]
{
    const int b   = blockIdx.x;
    const int tid = threadIdx.x;

    __shared__ float h_s[EDIM];
    __shared__ float v_s[EDIM];
    __shared__ float vap[4 * EDIM];       // phase A 4-way k-split partials
    __shared__ float p_s[TLEN];
    __shared__ float pbp[2 * TLEN];       // phase B 2-way k-split partials
    __shared__ float cxp[4 * EDIM];       // phase C 4-way t-split partials
    __shared__ float inp_s[2 * EDIM];
    __shared__ float inpn_s[2 * EDIM];
    __shared__ float gxp[4 * 768];        // phase D 4-way k-split partials (gx)
    __shared__ float ghp[4 * 768];        // phase D 4-way k-split partials (gh)
    __shared__ float scr[NWAVES];

    const float*        sigTb  = sigT + (size_t)b * EDIM * TLEN;
    const unsigned int* sigC2b = sigC2 + (size_t)b * (TLEN / 2) * EDIM;
    const int*          maskb  = mask + (size_t)b * TLEN;

    if (tid < EDIM) h_s[tid] = hinit[tid];
    __syncthreads();

    for (int s = 0; s < SLEN; ++s) {
        // ---- Phase A: v = Ww @ h + Wb. 256 rows x 4 k-quarters (64 k each), fp32
        {
            const int q   = tid >> 8;
            const int row = tid & 255;
            const float* col = WwT + (size_t)(q * 64) * EDIM + row;
            const float* xk = &h_s[q * 64];
            float a0 = 0.f, a1 = 0.f;
#pragma unroll 16
            for (int k = 0; k < 64; k += 2) {
                a0 += col[k * EDIM] * xk[k];
                a1 += col[(k + 1) * EDIM] * xk[k + 1];
            }
            vap[tid] = a0 + a1;
        }
        __syncthreads();
        if (tid < EDIM)
            v_s[tid] = vap[tid] + vap[EDIM + tid] + vap[2 * EDIM + tid] + vap[3 * EDIM + tid] + Wb[tid];
        __syncthreads();

        // ---- Phase B: e[t] = v . sig[t] via sigT fp32. 512 t x 2 k-halves (128 each)
        {
            const int half = tid >> 9;
            const int t    = tid & 511;
            const float* colT = sigTb + (size_t)(half * 128) * TLEN + t;
            const float* vk = &v_s[half * 128];
            float a0 = 0.f, a1 = 0.f, a2 = 0.f, a3 = 0.f;
#pragma unroll 8
            for (int k = 0; k < 128; k += 4) {
                a0 += colT[(k + 0) * TLEN] * vk[k + 0];
                a1 += colT[(k + 1) * TLEN] * vk[k + 1];
                a2 += colT[(k + 2) * TLEN] * vk[k + 2];
                a3 += colT[(k + 3) * TLEN] * vk[k + 3];
            }
            pbp[tid] = (a0 + a1) + (a2 + a3);
        }
        __syncthreads();
        if (tid < TLEN)
            p_s[tid] = maskb[tid] ? -1e30f : (pbp[tid] + pbp[TLEN + tid]);
        __syncthreads();

        // ---- softmax over T=512 (threads >=512 are identity) ----
        float e0 = (tid < TLEN) ? p_s[tid] : -1e30f;
        float M  = block_max(e0, scr, tid);
        float ex = __expf(e0 - M);                 // masked / idle -> 0
        if (tid < TLEN) p_s[tid] = ex;
        float Ssum = block_sum(ex, scr, tid);      // internal syncs publish p_s
        float inv  = 1.0f / Ssum;

        // ---- Phase C: ctx[e] = sum_t p[t]*sig[t][e]. 256 e x 4 t-quarters; fp16 signal
        {
            const int q = tid >> 8;
            const int e = tid & 255;
            const unsigned int* col = sigC2b + (size_t)(q * 64) * EDIM + e;
            const float* pk = &p_s[q * 128];
            float a0 = 0.f, a1 = 0.f;
#pragma unroll 16
            for (int i = 0; i < 64; ++i) {
                float2 f = h2f2(col[i * EDIM]);
                a0 += f.x * pk[2 * i];
                a1 += f.y * pk[2 * i + 1];
            }
            cxp[tid] = a0 + a1;
        }
        if (tid < EDIM) inp_s[tid] = bases[((size_t)b * SLEN + s) * EDIM + tid];
        __syncthreads();
        if (tid >= EDIM && tid < 2 * EDIM) {
            int e = tid - EDIM;
            inp_s[EDIM + e] = (cxp[e] + cxp[EDIM + e] + cxp[2 * EDIM + e] + cxp[3 * EDIM + e]) * inv;
        }
        __syncthreads();

        // ---- LayerNorm over 2E=512 (threads >=512 contribute 0) ----
        float val = (tid < 2 * EDIM) ? inp_s[tid] : 0.f;
        float mu  = block_sum(val, scr, tid) * (1.0f / (2 * EDIM));
        float dv  = val - mu;
        float dvv = (tid < 2 * EDIM) ? dv * dv : 0.f;
        float var = block_sum(dvv, scr, tid) * (1.0f / (2 * EDIM));
        float rs  = rsqrtf(var + 1e-5f);
        if (tid < 2 * EDIM) inpn_s[tid] = dv * rs * lng[tid] + lnb[tid];
        __syncthreads();

        // ---- Phase D: gx = wih@inpn (768x512), gh = whh@h (768x256); fp32, 4-way k-split
        // 3072 workers each, 3 rounds of NT; w = q*768+row (wave-uniform q: 768 = 12*64)
#pragma unroll
        for (int i = 0; i < 3; ++i) {
            int w   = i * NT + tid;
            int q   = w / 768;
            int row = w - q * 768;
            {
                const float* col = wihT + (size_t)(q * 128) * 768 + row;
                const float* xk = &inpn_s[q * 128];
                float a0 = 0.f, a1 = 0.f;
#pragma unroll 16
                for (int k = 0; k < 128; k += 2) {
                    a0 += col[k * 768] * xk[k];
                    a1 += col[(k + 1) * 768] * xk[k + 1];
                }
                gxp[w] = a0 + a1;
            }
            {
                const float* col = whhT + (size_t)(q * 64) * 768 + row;
                const float* xk = &h_s[q * 64];
                float a0 = 0.f, a1 = 0.f;
#pragma unroll 16
                for (int k = 0; k < 64; k += 2) {
                    a0 += col[k * 768] * xk[k];
                    a1 += col[(k + 1) * 768] * xk[k + 1];
                }
                ghp[w] = a0 + a1;
            }
        }
        __syncthreads();

        // ---- Phase E: gates, h update, output (torch gate order r,z,n) ----
        if (tid < EDIM) {
            int j = tid;
            float xr = bih[j], xz = bih[EDIM + j], xn = bih[2 * EDIM + j];
            float hr = bhh[j], hz = bhh[EDIM + j], hn_ = bhh[2 * EDIM + j];
#pragma unroll
            for (int q = 0; q < 4; ++q) {
                xr += gxp[q * 768 + j];
                xz += gxp[q * 768 + EDIM + j];
                xn += gxp[q * 768 + 2 * EDIM + j];
                hr += ghp[q * 768 + j];
                hz += ghp[q * 768 + EDIM + j];
                hn_ += ghp[q * 768 + 2 * EDIM + j];
            }
            float r = 1.0f / (1.0f + __expf(-(xr + hr)));
            float z = 1.0f / (1.0f + __expf(-(xz + hz)));
            float n = tanhf(xn + r * hn_);
            float hnew = (1.0f - z) * n + z * h_s[j];
            h_s[j] = hnew;
            out[((size_t)b * SLEN + s) * EDIM + j] = hnew;
        }
        __syncthreads();
    }
}

extern "C" void kernel_launch(void* const* d_in, const int* in_sizes, int n_in,
                              void* d_out, int out_size, void* d_ws, size_t ws_size,
                              hipStream_t stream) {
    const float* signal = (const float*)d_in[0];
    const float* bases  = (const float*)d_in[1];
    const int*   mask   = (const int*)d_in[2];
    const float* Ww     = (const float*)d_in[3];
    const float* Wb     = (const float*)d_in[4];
    const float* lng    = (const float*)d_in[5];
    const float* lnb    = (const float*)d_in[6];
    const float* wih    = (const float*)d_in[7];
    const float* bih    = (const float*)d_in[8];
    const float* whh    = (const float*)d_in[9];
    const float* bhh    = (const float*)d_in[10];
    const float* hinit  = (const float*)d_in[11];
    float*       out    = (float*)d_out;

    const int B = in_sizes[0] / (TLEN * EDIM);   // 128

    // workspace: sigT fp32 [B,E,T] | sigC2 u32 [B,T/2,E] (fp16x2) | WwT | wihT | whhT (fp32)
    float*        sigT  = (float*)d_ws;
    unsigned int* sigC2 = (unsigned int*)(sigT + (size_t)B * EDIM * TLEN);
    float*        WwT   = (float*)(sigC2 + (size_t)B * (TLEN / 2) * EDIM);
    float*        wihT  = WwT + EDIM * EDIM;
    float*        whhT  = wihT + (2 * EDIM) * (3 * EDIM);

    transpose_b_kernel<<<dim3(EDIM / 64, TLEN / 64, B), 256, 0, stream>>>(signal, sigT, TLEN, EDIM);
    pack_rows_h_kernel<<<dim3(B * (TLEN / 2) * EDIM / 256), 256, 0, stream>>>(signal, sigC2);
    transpose_b_kernel<<<dim3(EDIM / 64, EDIM / 64, 1), 256, 0, stream>>>(Ww, WwT, EDIM, EDIM);
    transpose_b_kernel<<<dim3(2 * EDIM / 64, 3 * EDIM / 64, 1), 256, 0, stream>>>(wih, wihT, 3 * EDIM, 2 * EDIM);
    transpose_b_kernel<<<dim3(EDIM / 64, 3 * EDIM / 64, 1), 256, 0, stream>>>(whh, whhT, 3 * EDIM, EDIM);

    gru_decoder_kernel<<<dim3(B), dim3(NT), 0, stream>>>(
        sigT, sigC2, bases, mask, WwT, Wb, lng, lnb, wihT, bih, whhT, bhh, hinit, out);
}

// Round 9
// 2737.891 us; speedup vs baseline: 2.6865x; 2.6865x over previous
//
#include <hip/hip_runtime.h>

// Problem constants (from reference)
#define EDIM 256
#define SLEN 64
#define TLEN 512
#define NT 512
#define NWAVES 8

// ---- wave/block reductions (softmax + LN only) ----
__device__ __forceinline__ float wred_sum(float v) {
#pragma unroll
    for (int m = 32; m > 0; m >>= 1) v += __shfl_xor(v, m, 64);
    return v;
}
__device__ __forceinline__ float wred_max(float v) {
#pragma unroll
    for (int m = 32; m > 0; m >>= 1) v = fmaxf(v, __shfl_xor(v, m, 64));
    return v;
}
__device__ __forceinline__ float block_sum(float v, float* scr, int tid) {
    v = wred_sum(v);
    if ((tid & 63) == 0) scr[tid >> 6] = v;
    __syncthreads();
    if (tid == 0) {
        float s = scr[0];
#pragma unroll
        for (int i = 1; i < NWAVES; ++i) s += scr[i];
        scr[0] = s;
    }
    __syncthreads();
    float r = scr[0];
    __syncthreads();
    return r;
}
__device__ __forceinline__ float block_max(float v, float* scr, int tid) {
    v = wred_max(v);
    if ((tid & 63) == 0) scr[tid >> 6] = v;
    __syncthreads();
    if (tid == 0) {
        float s = scr[0];
#pragma unroll
        for (int i = 1; i < NWAVES; ++i) s = fmaxf(s, scr[i]);
        scr[0] = s;
    }
    __syncthreads();
    float r = scr[0];
    __syncthreads();
    return r;
}

// ---- pre-pass: batched fp32 transpose  out[z][c][r] = in[z][r][c] ----
__global__ __launch_bounds__(256) void transpose_b_kernel(
    const float* __restrict__ in, float* __restrict__ out, int R, int C)
{
    __shared__ float tile[64][65];
    const float* inb = in + (size_t)blockIdx.z * R * C;
    float* outb = out + (size_t)blockIdx.z * R * C;
    const int r0 = blockIdx.y * 64;
    const int c0 = blockIdx.x * 64;
#pragma unroll
    for (int i = threadIdx.x; i < 64 * 64; i += 256) {
        int r = i >> 6, c = i & 63;
        tile[r][c] = inb[(size_t)(r0 + r) * C + (c0 + c)];
    }
    __syncthreads();
#pragma unroll
    for (int i = threadIdx.x; i < 64 * 64; i += 256) {
        int c = i >> 6, r = i & 63;
        outb[(size_t)(c0 + c) * R + (r0 + r)] = tile[r][c];
    }
}

__global__ __launch_bounds__(NT) void gru_decoder_kernel(
    const float* __restrict__ signal,       // [B,T,E] fp32 (phase C: rows of e)
    const float* __restrict__ sigT,         // [B,E,T] fp32 (phase B: rows of t)
    const float* __restrict__ bases,        // [B,S,E]
    const int* __restrict__ mask,           // [B,T] int32 (nonzero = masked)
    const float* __restrict__ WwT,          // [E,E]   WwT[k][j] = Ww[j][k]
    const float* __restrict__ Wb,           // [E]
    const float* __restrict__ lng,          // [2E]
    const float* __restrict__ lnb,          // [2E]
    const float* __restrict__ wihT,         // [2E,3E] wihT[k][j] = wih[j][k]
    const float* __restrict__ bih,          // [3E]
    const float* __restrict__ whhT,         // [E,3E]
    const float* __restrict__ bhh,          // [3E]
    const float* __restrict__ hinit,        // [E]
    float* __restrict__ out)                // [B,S,E]
{
    const int b   = blockIdx.x;
    const int tid = threadIdx.x;

    __shared__ float h_s[EDIM];
    __shared__ float v_s[EDIM];
    __shared__ float vap[8 * EDIM];       // phase A 8-way k-split partials
    __shared__ float p_s[TLEN];
    __shared__ float pbp[4 * TLEN];       // phase B 4-way k-split partials
    __shared__ float cxp[8 * EDIM];       // phase C 8-way t-split partials
    __shared__ float inp_s[2 * EDIM];
    __shared__ float inpn_s[2 * EDIM];
    __shared__ float gxp[4 * 768];        // phase D gx 4-way k-split partials
    __shared__ float ghp[4 * 768];        // phase D gh 4-way k-split partials
    __shared__ float scr[NWAVES];

    const float* sigb  = signal + (size_t)b * TLEN * EDIM;
    const float* sigTb = sigT + (size_t)b * EDIM * TLEN;
    const int*   maskb = mask + (size_t)b * TLEN;

    if (tid < EDIM) h_s[tid] = hinit[tid];
    __syncthreads();

    for (int s = 0; s < SLEN; ++s) {
        // ---- Phase A: v = Ww @ h + Wb. Thread owns 4 output rows (float4 loads),
        //      8-way k-split (32 k each). Wave load = 1KB contiguous.
        {
            const int q  = tid >> 6;            // 0..7 (wave-uniform)
            const int r4 = (tid & 63) * 4;      // 0..252
            const float* base = WwT + (size_t)(q * 32) * EDIM + r4;
            const float* xk = &h_s[q * 32];
            float a0 = 0.f, a1 = 0.f, a2 = 0.f, a3 = 0.f;
#pragma unroll 8
            for (int k = 0; k < 32; ++k) {
                float4 w4 = *reinterpret_cast<const float4*>(base + (size_t)k * EDIM);
                float x = xk[k];
                a0 += w4.x * x; a1 += w4.y * x; a2 += w4.z * x; a3 += w4.w * x;
            }
            vap[q * EDIM + r4 + 0] = a0;
            vap[q * EDIM + r4 + 1] = a1;
            vap[q * EDIM + r4 + 2] = a2;
            vap[q * EDIM + r4 + 3] = a3;
        }
        __syncthreads();
        if (tid < EDIM) {
            float v = Wb[tid];
#pragma unroll
            for (int q = 0; q < 8; ++q) v += vap[q * EDIM + tid];
            v_s[tid] = v;
        }
        __syncthreads();

        // ---- Phase B: e[t] = v . sig[t]. Thread owns 4 t (float4 from sigT rows),
        //      4-way k-split (64 k each).
        {
            const int q  = tid >> 7;            // 0..3 (wave-uniform)
            const int t4 = (tid & 127) * 4;     // 0..508
            const float* base = sigTb + (size_t)(q * 64) * TLEN + t4;
            const float* vk = &v_s[q * 64];
            float a0 = 0.f, a1 = 0.f, a2 = 0.f, a3 = 0.f;
#pragma unroll 8
            for (int k = 0; k < 64; ++k) {
                float4 w4 = *reinterpret_cast<const float4*>(base + (size_t)k * TLEN);
                float x = vk[k];
                a0 += w4.x * x; a1 += w4.y * x; a2 += w4.z * x; a3 += w4.w * x;
            }
            pbp[q * TLEN + t4 + 0] = a0;
            pbp[q * TLEN + t4 + 1] = a1;
            pbp[q * TLEN + t4 + 2] = a2;
            pbp[q * TLEN + t4 + 3] = a3;
        }
        __syncthreads();

        // ---- softmax over T=512 (thread t owns position t; NT==TLEN) ----
        float e0 = maskb[tid] ? -1e30f
                 : (pbp[tid] + pbp[TLEN + tid] + pbp[2 * TLEN + tid] + pbp[3 * TLEN + tid]);
        float M  = block_max(e0, scr, tid);
        float ex = __expf(e0 - M);              // masked: exp(-1e30 - M) -> 0
        p_s[tid] = ex;
        float Ssum = block_sum(ex, scr, tid);   // internal barrier publishes p_s
        float inv  = 1.0f / Ssum;

        // ---- Phase C: ctx[e] = sum_t p[t]*sig[t][e]. Thread owns 4 e (float4),
        //      8-way t-split (64 t each).
        {
            const int q  = tid >> 6;            // 0..7 (wave-uniform)
            const int e4 = (tid & 63) * 4;      // 0..252
            const float* base = sigb + (size_t)(q * 64) * EDIM + e4;
            const float* pk = &p_s[q * 64];
            float a0 = 0.f, a1 = 0.f, a2 = 0.f, a3 = 0.f;
#pragma unroll 8
            for (int t = 0; t < 64; ++t) {
                float4 w4 = *reinterpret_cast<const float4*>(base + (size_t)t * EDIM);
                float p = pk[t];
                a0 += w4.x * p; a1 += w4.y * p; a2 += w4.z * p; a3 += w4.w * p;
            }
            cxp[q * EDIM + e4 + 0] = a0;
            cxp[q * EDIM + e4 + 1] = a1;
            cxp[q * EDIM + e4 + 2] = a2;
            cxp[q * EDIM + e4 + 3] = a3;
        }
        if (tid < EDIM) inp_s[tid] = bases[((size_t)b * SLEN + s) * EDIM + tid];
        __syncthreads();
        if (tid >= EDIM) {
            int e = tid - EDIM;
            float c = 0.f;
#pragma unroll
            for (int q = 0; q < 8; ++q) c += cxp[q * EDIM + e];
            inp_s[EDIM + e] = c * inv;
        }
        __syncthreads();

        // ---- LayerNorm over 2E=512 (thread per element; NT==2E) ----
        float val = inp_s[tid];
        float mu  = block_sum(val, scr, tid) * (1.0f / (2 * EDIM));
        float dv  = val - mu;
        float var = block_sum(dv * dv, scr, tid) * (1.0f / (2 * EDIM));
        float rs  = rsqrtf(var + 1e-5f);
        inpn_s[tid] = dv * rs * lng[tid] + lnb[tid];
        __syncthreads();

        // ---- Phase D: gx = wih@inpn (768x512), gh = whh@h (768x256).
        //      1536 workers over 3 rounds; worker owns 4 rows (float4), 4-way k-split.
        //      Branch boundary at w=768 is a wave boundary (768=12*64); q=w/192 is
        //      wave-uniform (192=3*64).
#pragma unroll
        for (int rd = 0; rd < 3; ++rd) {
            int w = rd * NT + tid;              // 0..1535
            if (w < 768) {                      // gx worker
                int q  = w / 192;               // 0..3 -> k in [q*128, q*128+128)
                int r4 = (w - q * 192) * 4;     // 0..764
                const float* base = wihT + (size_t)(q * 128) * 768 + r4;
                const float* xk = &inpn_s[q * 128];
                float a0 = 0.f, a1 = 0.f, a2 = 0.f, a3 = 0.f;
#pragma unroll 8
                for (int k = 0; k < 128; ++k) {
                    float4 w4 = *reinterpret_cast<const float4*>(base + (size_t)k * 768);
                    float x = xk[k];
                    a0 += w4.x * x; a1 += w4.y * x; a2 += w4.z * x; a3 += w4.w * x;
                }
                gxp[q * 768 + r4 + 0] = a0;
                gxp[q * 768 + r4 + 1] = a1;
                gxp[q * 768 + r4 + 2] = a2;
                gxp[q * 768 + r4 + 3] = a3;
            } else {                            // gh worker
                int w2 = w - 768;
                int q  = w2 / 192;              // 0..3 -> k in [q*64, q*64+64)
                int r4 = (w2 - q * 192) * 4;
                const float* base = whhT + (size_t)(q * 64) * 768 + r4;
                const float* xk = &h_s[q * 64];
                float a0 = 0.f, a1 = 0.f, a2 = 0.f, a3 = 0.f;
#pragma unroll 8
                for (int k = 0; k < 64; ++k) {
                    float4 w4 = *reinterpret_cast<const float4*>(base + (size_t)k * 768);
                    float x = xk[k];
                    a0 += w4.x * x; a1 += w4.y * x; a2 += w4.z * x; a3 += w4.w * x;
                }
                ghp[q * 768 + r4 + 0] = a0;
                ghp[q * 768 + r4 + 1] = a1;
                ghp[q * 768 + r4 + 2] = a2;
                ghp[q * 768 + r4 + 3] = a3;
            }
        }
        __syncthreads();

        // ---- Phase E: gates, h update, output (torch gate order r,z,n) ----
        if (tid < EDIM) {
            int j = tid;
            float xr = bih[j], xz = bih[EDIM + j], xn = bih[2 * EDIM + j];
            float hr = bhh[j], hz = bhh[EDIM + j], hn_ = bhh[2 * EDIM + j];
#pragma unroll
            for (int q = 0; q < 4; ++q) {
                xr  += gxp[q * 768 + j];
                xz  += gxp[q * 768 + EDIM + j];
                xn  += gxp[q * 768 + 2 * EDIM + j];
                hr  += ghp[q * 768 + j];
                hz  += ghp[q * 768 + EDIM + j];
                hn_ += ghp[q * 768 + 2 * EDIM + j];
            }
            float r = 1.0f / (1.0f + __expf(-(xr + hr)));
            float z = 1.0f / (1.0f + __expf(-(xz + hz)));
            float n = tanhf(xn + r * hn_);
            float hnew = (1.0f - z) * n + z * h_s[j];
            h_s[j] = hnew;
            out[((size_t)b * SLEN + s) * EDIM + j] = hnew;
        }
        __syncthreads();
    }
}

extern "C" void kernel_launch(void* const* d_in, const int* in_sizes, int n_in,
                              void* d_out, int out_size, void* d_ws, size_t ws_size,
                              hipStream_t stream) {
    const float* signal = (const float*)d_in[0];
    const float* bases  = (const float*)d_in[1];
    const int*   mask   = (const int*)d_in[2];
    const float* Ww     = (const float*)d_in[3];
    const float* Wb     = (const float*)d_in[4];
    const float* lng    = (const float*)d_in[5];
    const float* lnb    = (const float*)d_in[6];
    const float* wih    = (const float*)d_in[7];
    const float* bih    = (const float*)d_in[8];
    const float* whh    = (const float*)d_in[9];
    const float* bhh    = (const float*)d_in[10];
    const float* hinit  = (const float*)d_in[11];
    float*       out    = (float*)d_out;

    const int B = in_sizes[0] / (TLEN * EDIM);   // 128

    // workspace (all fp32): sigT[B,E,T] | WwT[E,E] | wihT[2E,3E] | whhT[E,3E]
    float* sigT = (float*)d_ws;
    float* WwT  = sigT + (size_t)B * EDIM * TLEN;
    float* wihT = WwT + EDIM * EDIM;
    float* whhT = wihT + (2 * EDIM) * (3 * EDIM);

    transpose_b_kernel<<<dim3(EDIM / 64, TLEN / 64, B), 256, 0, stream>>>(signal, sigT, TLEN, EDIM);
    transpose_b_kernel<<<dim3(EDIM / 64, EDIM / 64, 1), 256, 0, stream>>>(Ww, WwT, EDIM, EDIM);
    transpose_b_kernel<<<dim3(2 * EDIM / 64, 3 * EDIM / 64, 1), 256, 0, stream>>>(wih, wihT, 3 * EDIM, 2 * EDIM);
    transpose_b_kernel<<<dim3(EDIM / 64, 3 * EDIM / 64, 1), 256, 0, stream>>>(whh, whhT, 3 * EDIM, EDIM);

    gru_decoder_kernel<<<dim3(B), dim3(NT), 0, stream>>>(
        signal, sigT, bases, mask, WwT, Wb, lng, lnb, wihT, bih, whhT, bhh, hinit, out);
}